// Round 6
// baseline (628.252 us; speedup 1.0000x reference)
//
#include <hip/hip_runtime.h>

typedef __bf16 bf16x8 __attribute__((ext_vector_type(8)));
typedef unsigned short u16x8 __attribute__((ext_vector_type(8)));
typedef float f32x4 __attribute__((ext_vector_type(4)));
typedef unsigned short u16;

__device__ __forceinline__ float bf2f(u16 u) {
    union { unsigned int i; float f; } x; x.i = ((unsigned int)u) << 16; return x.f;
}
__device__ __forceinline__ u16 f2bf(float f) {
    union { float f; unsigned int i; } x; x.f = f;
    unsigned int u = x.i;
    unsigned int r = (u + 0x7FFFu + ((u >> 16) & 1u)) >> 16;
    return (u16)r;
}

#define GL16(g, l) __builtin_amdgcn_global_load_lds( \
    (__attribute__((address_space(1))) void*)(void*)(g), \
    (__attribute__((address_space(3))) void*)(void*)(l), 16, 0, 0)

// ---------------------------------------------------------------------------
// weights fp32 -> bf16
// ---------------------------------------------------------------------------
__global__ __launch_bounds__(256)
void cvt6_kernel(const float* __restrict__ s0, const float* __restrict__ s1,
                 const float* __restrict__ s2, const float* __restrict__ s3,
                 const float* __restrict__ s4, const float* __restrict__ s5,
                 u16* __restrict__ d0, u16* __restrict__ d1, u16* __restrict__ d2,
                 u16* __restrict__ d3, u16* __restrict__ d4, u16* __restrict__ d5)
{
    int b = blockIdx.x;
    const float* s; u16* d; int base;
    if (b < 512) {
        int t = b >> 7, lb = b & 127;
        s = (t == 0) ? s0 : (t == 1) ? s1 : (t == 2) ? s2 : s3;
        d = (t == 0) ? d0 : (t == 1) ? d1 : (t == 2) ? d2 : d3;
        base = lb * 2048;
    } else if (b < 1024) { s = s4; d = d4; base = (b - 512) * 2048; }
    else                 { s = s5; d = d5; base = (b - 1024) * 2048; }
    int i = base + threadIdx.x * 8;
    float4 a = *(const float4*)&s[i];
    float4 c = *(const float4*)&s[i + 4];
    u16x8 o;
    o[0] = f2bf(a.x); o[1] = f2bf(a.y); o[2] = f2bf(a.z); o[3] = f2bf(a.w);
    o[4] = f2bf(c.x); o[5] = f2bf(c.y); o[6] = f2bf(c.z); o[7] = f2bf(c.w);
    *(u16x8*)&d[i] = o;
}

// ---------------------------------------------------------------------------
// bias[i][j] = alpha*softmax_j(relu(E E^T)) + beta*lap + (lap!=0?0:-1e9)
// ---------------------------------------------------------------------------
__global__ __launch_bounds__(256)
void bias_kernel(const float* __restrict__ E, const float* __restrict__ lap,
                 const float* __restrict__ alpha_p, const float* __restrict__ beta_p,
                 float* __restrict__ biasout)
{
    __shared__ float wred[8];
    int tid = threadIdx.x;
    int i = blockIdx.x;
    int lane = tid & 63, wave = tid >> 6;
    int j0 = tid, j1 = tid + 256;
    float s0 = 0.f, s1 = 0.f;
#pragma unroll
    for (int t4 = 0; t4 < 16; ++t4) {
        float4 a  = *(const float4*)&E[i * 64 + t4 * 4];
        float4 e0 = *(const float4*)&E[j0 * 64 + t4 * 4];
        float4 e1 = *(const float4*)&E[j1 * 64 + t4 * 4];
        s0 += a.x * e0.x + a.y * e0.y + a.z * e0.z + a.w * e0.w;
        s1 += a.x * e1.x + a.y * e1.y + a.z * e1.z + a.w * e1.w;
    }
    s0 = fmaxf(s0, 0.f); s1 = fmaxf(s1, 0.f);
    float m = fmaxf(s0, s1);
#pragma unroll
    for (int o = 32; o > 0; o >>= 1) m = fmaxf(m, __shfl_xor(m, o));
    if (lane == 0) wred[wave] = m;
    __syncthreads();
    m = fmaxf(fmaxf(wred[0], wred[1]), fmaxf(wred[2], wred[3]));
    float e0v = __expf(s0 - m), e1v = __expf(s1 - m);
    float sum = e0v + e1v;
#pragma unroll
    for (int o = 32; o > 0; o >>= 1) sum += __shfl_xor(sum, o);
    if (lane == 0) wred[4 + wave] = sum;
    __syncthreads();
    float inv = 1.f / (wred[4] + wred[5] + wred[6] + wred[7]);
    float alpha = alpha_p[0], beta = beta_p[0];
    float lv0 = lap[i * 512 + j0];
    float lv1 = lap[i * 512 + j1];
    biasout[i * 512 + j0] = alpha * (e0v * inv) + beta * lv0 + (lv0 != 0.f ? 0.f : -1e9f);
    biasout[i * 512 + j1] = alpha * (e1v * inv) + beta * lv1 + (lv1 != 0.f ? 0.f : -1e9f);
}

// ---------------------------------------------------------------------------
// LayerNorm D=512, fp32 in, bf16 out
// ---------------------------------------------------------------------------
__global__ __launch_bounds__(256)
void ln_kernel(const float* __restrict__ X, const float* __restrict__ G,
               const float* __restrict__ Bb, u16* __restrict__ Y)
{
    int row = blockIdx.x * 4 + (threadIdx.x >> 6);
    int lane = threadIdx.x & 63;
    const float* xr = X + (size_t)row * 512 + lane * 8;
    float4 a = *(const float4*)xr;
    float4 b = *(const float4*)(xr + 4);
    float v[8] = {a.x, a.y, a.z, a.w, b.x, b.y, b.z, b.w};
    float s = 0.f, ss = 0.f;
#pragma unroll
    for (int i = 0; i < 8; i++) { s += v[i]; ss += v[i] * v[i]; }
#pragma unroll
    for (int o = 32; o > 0; o >>= 1) { s += __shfl_xor(s, o); ss += __shfl_xor(ss, o); }
    float mu = s * (1.f / 512.f);
    float var = ss * (1.f / 512.f) - mu * mu;
    float rstd = rsqrtf(var + 1e-5f);
    float4 g0 = *(const float4*)&G[lane * 8];
    float4 g1 = *(const float4*)&G[lane * 8 + 4];
    float4 b0 = *(const float4*)&Bb[lane * 8];
    float4 b1 = *(const float4*)&Bb[lane * 8 + 4];
    float gv[8] = {g0.x, g0.y, g0.z, g0.w, g1.x, g1.y, g1.z, g1.w};
    float bv[8] = {b0.x, b0.y, b0.z, b0.w, b1.x, b1.y, b1.z, b1.w};
    u16x8 out;
#pragma unroll
    for (int i = 0; i < 8; i++) out[i] = f2bf((v[i] - mu) * rstd * gv[i] + bv[i]);
    *(u16x8*)&Y[(size_t)row * 512 + lane * 8] = out;
}

// ---------------------------------------------------------------------------
// Barrier-free direct-to-VGPR GEMM: C = A[M,Kd] @ W[Nout,Kd]^T + bias.
// No LDS, no __syncthreads -> compiler interleaves global loads with MFMA
// using fine-grained vmcnt (AITER-style). 128x128 tile, 4 waves (2x2),
// explicit 2-deep k-pipeline. XCD-swizzled row-slabs.
// mode 0 plain->bf16, 1 relu->bf16, 2 +resid(fp32)->fp32
// ---------------------------------------------------------------------------
__global__ __launch_bounds__(256)
void gemm_direct(const u16* __restrict__ A, const u16* __restrict__ W,
                 const float* __restrict__ bias, const float* __restrict__ resid,
                 u16* __restrict__ Cb, float* __restrict__ Cf,
                 int M, int Kd, int Nout, int mode)
{
    int tid = threadIdx.x;
    int lane = tid & 63, wave = tid >> 6;
    int wm = wave >> 1, wn = wave & 1;
    int bid = blockIdx.y * gridDim.x + blockIdx.x;
    int per = (gridDim.x * gridDim.y) >> 3;
    int lb  = (bid & 7) * per + (bid >> 3);
    int bx = lb % gridDim.x, by = lb / gridDim.x;
    int row0 = by * 128, col0 = bx * 128;
    int rl = lane & 15, kq = lane >> 4;

    const u16* Ap = A + (size_t)(row0 + wm * 64 + rl) * Kd + kq * 8;
    const u16* Wp = W + (size_t)(col0 + wn * 64 + rl) * Kd + kq * 8;
    const size_t fstep = (size_t)16 * Kd;   // 16 rows per frag step

    f32x4 acc[4][4];
#pragma unroll
    for (int i = 0; i < 4; i++)
#pragma unroll
        for (int j = 0; j < 4; j++) acc[i][j] = (f32x4){0.f, 0.f, 0.f, 0.f};

    bf16x8 ac[4], bc[4];
#pragma unroll
    for (int i = 0; i < 4; i++) ac[i] = *(const bf16x8*)(Ap + i * fstep);
#pragma unroll
    for (int j = 0; j < 4; j++) bc[j] = *(const bf16x8*)(Wp + j * fstep);

    for (int k0 = 32; k0 < Kd; k0 += 32) {
        bf16x8 an[4], bn[4];
#pragma unroll
        for (int i = 0; i < 4; i++) an[i] = *(const bf16x8*)(Ap + i * fstep + k0);
#pragma unroll
        for (int j = 0; j < 4; j++) bn[j] = *(const bf16x8*)(Wp + j * fstep + k0);
#pragma unroll
        for (int i = 0; i < 4; i++)
#pragma unroll
            for (int j = 0; j < 4; j++)
                acc[i][j] = __builtin_amdgcn_mfma_f32_16x16x32_bf16(ac[i], bc[j], acc[i][j], 0, 0, 0);
#pragma unroll
        for (int i = 0; i < 4; i++) ac[i] = an[i];
#pragma unroll
        for (int j = 0; j < 4; j++) bc[j] = bn[j];
    }
#pragma unroll
    for (int i = 0; i < 4; i++)
#pragma unroll
        for (int j = 0; j < 4; j++)
            acc[i][j] = __builtin_amdgcn_mfma_f32_16x16x32_bf16(ac[i], bc[j], acc[i][j], 0, 0, 0);

    int kq4 = (lane >> 4) * 4;
#pragma unroll
    for (int j = 0; j < 4; j++) {
        int col = col0 + wn * 64 + j * 16 + rl;
        float bsv = bias[col];
#pragma unroll
        for (int i = 0; i < 4; i++) {
            int rbase = row0 + wm * 64 + i * 16 + kq4;
#pragma unroll
            for (int r = 0; r < 4; r++) {
                float vo = acc[i][j][r] + bsv;
                size_t idx = (size_t)(rbase + r) * Nout + col;
                if (mode == 2)      Cf[idx] = vo + resid[idx];
                else if (mode == 1) Cb[idx] = f2bf(fmaxf(vo, 0.f));
                else                Cb[idx] = f2bf(vo);
            }
        }
    }
}

// ---------------------------------------------------------------------------
// fused QKV, barrier-free direct version. grid 12 x 128 (sel = rest>>2).
// ---------------------------------------------------------------------------
__global__ __launch_bounds__(256)
void gemm_qkv(const u16* __restrict__ A,
              const u16* __restrict__ W0, const u16* __restrict__ W1, const u16* __restrict__ W2,
              const float* __restrict__ b0, const float* __restrict__ b1, const float* __restrict__ b2,
              u16* __restrict__ C0, u16* __restrict__ C1, u16* __restrict__ C2)
{
    const int Kd = 512, Nout = 512;
    int bid = blockIdx.y * gridDim.x + blockIdx.x;
    int per = (gridDim.x * gridDim.y) >> 3;       // 192
    int lb  = (bid & 7) * per + (bid >> 3);
    int rest = lb % 12, by = lb / 12;
    int sel = rest >> 2;
    const u16* W = (sel == 0) ? W0 : (sel == 1) ? W1 : W2;
    const float* bias = (sel == 0) ? b0 : (sel == 1) ? b1 : b2;
    u16* Cb = (sel == 0) ? C0 : (sel == 1) ? C1 : C2;
    int tid = threadIdx.x;
    int lane = tid & 63, wave = tid >> 6;
    int wm = wave >> 1, wn = wave & 1;
    int row0 = by * 128, col0 = (rest & 3) * 128;
    int rl = lane & 15, kq = lane >> 4;

    const u16* Ap = A + (size_t)(row0 + wm * 64 + rl) * Kd + kq * 8;
    const u16* Wp = W + (size_t)(col0 + wn * 64 + rl) * Kd + kq * 8;
    const size_t fstep = (size_t)16 * Kd;

    f32x4 acc[4][4];
#pragma unroll
    for (int i = 0; i < 4; i++)
#pragma unroll
        for (int j = 0; j < 4; j++) acc[i][j] = (f32x4){0.f, 0.f, 0.f, 0.f};

    bf16x8 ac[4], bc[4];
#pragma unroll
    for (int i = 0; i < 4; i++) ac[i] = *(const bf16x8*)(Ap + i * fstep);
#pragma unroll
    for (int j = 0; j < 4; j++) bc[j] = *(const bf16x8*)(Wp + j * fstep);

    for (int k0 = 32; k0 < Kd; k0 += 32) {
        bf16x8 an[4], bn[4];
#pragma unroll
        for (int i = 0; i < 4; i++) an[i] = *(const bf16x8*)(Ap + i * fstep + k0);
#pragma unroll
        for (int j = 0; j < 4; j++) bn[j] = *(const bf16x8*)(Wp + j * fstep + k0);
#pragma unroll
        for (int i = 0; i < 4; i++)
#pragma unroll
            for (int j = 0; j < 4; j++)
                acc[i][j] = __builtin_amdgcn_mfma_f32_16x16x32_bf16(ac[i], bc[j], acc[i][j], 0, 0, 0);
#pragma unroll
        for (int i = 0; i < 4; i++) ac[i] = an[i];
#pragma unroll
        for (int j = 0; j < 4; j++) bc[j] = bn[j];
    }
#pragma unroll
    for (int i = 0; i < 4; i++)
#pragma unroll
        for (int j = 0; j < 4; j++)
            acc[i][j] = __builtin_amdgcn_mfma_f32_16x16x32_bf16(ac[i], bc[j], acc[i][j], 0, 0, 0);

    int kq4 = (lane >> 4) * 4;
#pragma unroll
    for (int j = 0; j < 4; j++) {
        int col = col0 + wn * 64 + j * 16 + rl;
        float bsv = bias[col];
#pragma unroll
        for (int i = 0; i < 4; i++) {
            int rbase = row0 + wm * 64 + i * 16 + kq4;
#pragma unroll
            for (int r = 0; r < 4; r++)
                Cb[(size_t)(rbase + r) * Nout + col] = f2bf(acc[i][j][r] + bsv);
        }
    }
}

// ---------------------------------------------------------------------------
// flash attention: block = (qtile 128 rows) x (bt,h); 4 kv-tiles of 128,
// online softmax; O accum in regs. grid (4, 8, 32), block 256 (4 waves 2x2).
// ---------------------------------------------------------------------------
__global__ __launch_bounds__(256, 2)
void flash_attn(const u16* __restrict__ Q, const u16* __restrict__ Km,
                const u16* __restrict__ V, const float* __restrict__ biasP,
                u16* __restrict__ O)
{
    __shared__ __align__(16) u16 lQ[128 * 64];            // 16 KB [q][d]
    __shared__ __align__(16) u16 lPK[128 * 136];          // 34 KB: K tile (linear) / P (stride 136)
    __shared__ __align__(16) unsigned int lVt[64 * 68];   // 17 KB: V^T [e][kv-pair], stride 68 u32
    __shared__ float red[2 * 128];
    __shared__ float m_s[128], l_s[128], alpha_s[128], mnew_s[128];

    int tid = threadIdx.x, lane = tid & 63, wave = tid >> 6;
    int wm = wave >> 1, wn = wave & 1;
    int rl = lane & 15, kq = lane >> 4;
    int qt = blockIdx.x, h = blockIdx.y, bt = blockIdx.z;
    int qg0 = qt * 128;
    size_t hb = (size_t)bt * (512 * 512) + h * 64;
    const u16* Qbase = Q + hb + (size_t)qg0 * 512;
    const u16* Kb0   = Km + hb;
    const u16* Vb0   = V + hb;

    // stage Q (once)
#pragma unroll
    for (int rep = 0; rep < 4; ++rep) {
        int c = rep * 256 + tid;
        int qr = c >> 3, d0 = (c & 7) * 8;
        GL16(Qbase + (size_t)qr * 512 + d0, &lQ[c * 8]);
    }
    if (tid < 128) { m_s[tid] = -3.0e38f; l_s[tid] = 0.f; }
    __syncthreads();

    bf16x8 af[4][2];
#pragma unroll
    for (int i = 0; i < 4; i++)
#pragma unroll
        for (int s = 0; s < 2; s++)
            af[i][s] = *(const bf16x8*)&lQ[(wm * 64 + i * 16 + rl) * 64 + s * 32 + kq * 8];

    f32x4 o[4][2];
#pragma unroll
    for (int i = 0; i < 4; i++)
#pragma unroll
        for (int jj = 0; jj < 2; jj++) o[i][jj] = (f32x4){0.f, 0.f, 0.f, 0.f};

    for (int t = 0; t < 4; ++t) {
        int kv0 = t * 128;
        __syncthreads();   // prior PV reads of lPK/lVt done
        // stage K tile -> lPK (linear [kv][64])
        const u16* Kbase = Kb0 + (size_t)kv0 * 512;
#pragma unroll
        for (int rep = 0; rep < 4; ++rep) {
            int c = rep * 256 + tid;
            int kv = c >> 3, d0 = (c & 7) * 8;
            GL16(Kbase + (size_t)kv * 512 + d0, &lPK[c * 8]);
        }
        // stage V^T (paired-row b32 writes, bank = p%32 -> 2-way, free)
        const u16* Vbase = Vb0 + (size_t)kv0 * 512;
#pragma unroll
        for (int rep = 0; rep < 2; ++rep) {
            int idx = rep * 256 + tid;
            int p = idx & 63, e0 = (idx >> 6) * 8;
            const u16* vp0 = Vbase + (size_t)(2 * p) * 512 + e0;
            u16x8 v0 = *(const u16x8*)vp0;
            u16x8 v1 = *(const u16x8*)(vp0 + 512);
#pragma unroll
            for (int u = 0; u < 8; ++u)
                lVt[(e0 + u) * 68 + p] = (unsigned)v0[u] | ((unsigned)v1[u] << 16);
        }
        __syncthreads();   // staging complete

        // S = Q K^T * 0.125 + bias
        f32x4 acc[4][4];
#pragma unroll
        for (int j = 0; j < 4; ++j) {
            bf16x8 bk0 = *(const bf16x8*)&lPK[(wn * 64 + j * 16 + rl) * 64 + kq * 8];
            bf16x8 bk1 = *(const bf16x8*)&lPK[(wn * 64 + j * 16 + rl) * 64 + 32 + kq * 8];
#pragma unroll
            for (int i = 0; i < 4; ++i) {
                acc[i][j] = __builtin_amdgcn_mfma_f32_16x16x32_bf16(af[i][0], bk0,
                            (f32x4){0.f, 0.f, 0.f, 0.f}, 0, 0, 0);
                acc[i][j] = __builtin_amdgcn_mfma_f32_16x16x32_bf16(af[i][1], bk1, acc[i][j], 0, 0, 0);
            }
        }
#pragma unroll
        for (int i = 0; i < 4; ++i)
#pragma unroll
            for (int j = 0; j < 4; ++j) {
                int colg = kv0 + wn * 64 + j * 16 + rl;
                const float* bp = biasP + (size_t)(qg0 + wm * 64 + i * 16 + kq * 4) * 512 + colg;
#pragma unroll
                for (int r = 0; r < 4; ++r)
                    acc[i][j][r] = acc[i][j][r] * 0.125f + bp[(size_t)r * 512];
            }

        // per-tile row max -> red
#pragma unroll
        for (int i = 0; i < 4; ++i) {
            float mx[4];
#pragma unroll
            for (int r = 0; r < 4; ++r) {
                mx[r] = fmaxf(fmaxf(acc[i][0][r], acc[i][1][r]), fmaxf(acc[i][2][r], acc[i][3][r]));
#pragma unroll
                for (int off = 8; off > 0; off >>= 1) mx[r] = fmaxf(mx[r], __shfl_xor(mx[r], off));
            }
            if (rl == 0) {
#pragma unroll
                for (int r = 0; r < 4; ++r)
                    red[wn * 128 + wm * 64 + i * 16 + kq * 4 + r] = mx[r];
            }
        }
        __syncthreads();
        if (tid < 128) {
            float pm = fmaxf(red[tid], red[128 + tid]);
            float mo = m_s[tid];
            float mn = fmaxf(mo, pm);
            m_s[tid] = mn; mnew_s[tid] = mn;
            alpha_s[tid] = __expf(mo - mn);
        }
        __syncthreads();

        // P = exp(S - m_new); write lP; row sums; rescale O
#pragma unroll
        for (int i = 0; i < 4; ++i) {
            int rb = wm * 64 + i * 16 + kq * 4;
            float mn[4], al[4], sm[4];
#pragma unroll
            for (int r = 0; r < 4; ++r) { mn[r] = mnew_s[rb + r]; al[r] = alpha_s[rb + r]; sm[r] = 0.f; }
#pragma unroll
            for (int j = 0; j < 4; ++j) {
                int col = wn * 64 + j * 16 + rl;
#pragma unroll
                for (int r = 0; r < 4; ++r) {
                    float p = __expf(acc[i][j][r] - mn[r]);
                    sm[r] += p;
                    lPK[(rb + r) * 136 + col] = f2bf(p);
                }
            }
#pragma unroll
            for (int jj = 0; jj < 2; ++jj)
#pragma unroll
                for (int r = 0; r < 4; ++r) o[i][jj][r] *= al[r];
#pragma unroll
            for (int r = 0; r < 4; ++r) {
#pragma unroll
                for (int off = 8; off > 0; off >>= 1) sm[r] += __shfl_xor(sm[r], off);
            }
            if (rl == 0) {
#pragma unroll
                for (int r = 0; r < 4; ++r) red[wn * 128 + rb + r] = sm[r];
            }
        }
        __syncthreads();
        if (tid < 128) l_s[tid] = l_s[tid] * alpha_s[tid] + red[tid] + red[128 + tid];

        // O += P V  (A-frags from lP stride 136; B-frags from lVt:
        //  kv pairs packed in u32 -> u32 offset X must satisfy 2X = ks*32+kq*8)
#pragma unroll
        for (int ks = 0; ks < 4; ++ks) {
            bf16x8 aP[4], bV[2];
#pragma unroll
            for (int i = 0; i < 4; ++i)
                aP[i] = *(const bf16x8*)&lPK[(wm * 64 + i * 16 + rl) * 136 + ks * 32 + kq * 8];
#pragma unroll
            for (int jj = 0; jj < 2; ++jj)
                bV[jj] = *(const bf16x8*)&lVt[(wn * 32 + jj * 16 + rl) * 68 + ks * 16 + kq * 4];
#pragma unroll
            for (int i = 0; i < 4; ++i)
#pragma unroll
                for (int jj = 0; jj < 2; ++jj)
                    o[i][jj] = __builtin_amdgcn_mfma_f32_16x16x32_bf16(aP[i], bV[jj], o[i][jj], 0, 0, 0);
        }
    }
    __syncthreads();

    // epilogue: O /= l, write bf16
    u16* Ob = O + hb + (size_t)qg0 * 512;
#pragma unroll
    for (int i = 0; i < 4; ++i) {
        int rb = wm * 64 + i * 16 + kq * 4;
        float il[4];
#pragma unroll
        for (int r = 0; r < 4; ++r) il[r] = 1.f / l_s[rb + r];
#pragma unroll
        for (int jj = 0; jj < 2; ++jj) {
            int e = wn * 32 + jj * 16 + rl;
#pragma unroll
            for (int r = 0; r < 4; ++r)
                Ob[(size_t)(rb + r) * 512 + e] = f2bf(o[i][jj][r] * il[r]);
        }
    }
}

// ---------------------------------------------------------------------------
extern "C" void kernel_launch(void* const* d_in, const int* in_sizes, int n_in,
                              void* d_out, int out_size, void* d_ws, size_t ws_size,
                              hipStream_t stream)
{
    const float* x     = (const float*)d_in[0];
    const float* lap   = (const float*)d_in[1];
    const float* emb   = (const float*)d_in[2];
    const float* Wq    = (const float*)d_in[3];
    const float* bq    = (const float*)d_in[4];
    const float* Wk    = (const float*)d_in[5];
    const float* bk    = (const float*)d_in[6];
    const float* Wv    = (const float*)d_in[7];
    const float* bvv   = (const float*)d_in[8];
    const float* g1    = (const float*)d_in[9];
    const float* bb1   = (const float*)d_in[10];
    const float* g2    = (const float*)d_in[11];
    const float* bb2   = (const float*)d_in[12];
    const float* alpha = (const float*)d_in[13];
    const float* beta  = (const float*)d_in[14];
    const float* Wo    = (const float*)d_in[15];
    const float* bo    = (const float*)d_in[16];
    const float* W1    = (const float*)d_in[17];
    const float* b1    = (const float*)d_in[18];
    const float* W2    = (const float*)d_in[19];
    const float* b2    = (const float*)d_in[20];
    float* out = (float*)d_out;

    const size_t SZ = (size_t)4 * 8 * 512 * 512;
    char* w = (char*)d_ws;
    float* bias = (float*)w;  w += (size_t)512 * 512 * 4;
    u16* wqb = (u16*)w; w += (size_t)512 * 512 * 2;
    u16* wkb = (u16*)w; w += (size_t)512 * 512 * 2;
    u16* wvb = (u16*)w; w += (size_t)512 * 512 * 2;
    u16* wob = (u16*)w; w += (size_t)512 * 512 * 2;
    u16* w1b = (u16*)w; w += (size_t)2048 * 512 * 2;
    u16* w2b = (u16*)w; w += (size_t)512 * 2048 * 2;
    u16* xnb = (u16*)w; w += SZ * 2;   // LN1 out; reused as attention output
    u16* qb  = (u16*)w; w += SZ * 2;   // Q; reused as LN2 out
    u16* kb  = (u16*)w; w += SZ * 2;
    u16* vb  = (u16*)w; w += SZ * 2;
    u16* hb  = (u16*)w; w += (size_t)16384 * 2048 * 2;
    float* x1 = out;

    const int M = 16384;
    cvt6_kernel<<<1536, 256, 0, stream>>>(Wq, Wk, Wv, Wo, W1, W2,
                                          wqb, wkb, wvb, wob, w1b, w2b);
    bias_kernel<<<512, 256, 0, stream>>>(emb, lap, alpha, beta, bias);
    ln_kernel<<<M / 4, 256, 0, stream>>>(x, g1, bb1, xnb);
    gemm_qkv<<<dim3(12, 128), 256, 0, stream>>>(xnb, wqb, wkb, wvb, bq, bk, bvv, qb, kb, vb);
    flash_attn<<<dim3(4, 8, 32), 256, 0, stream>>>(qb, kb, vb, bias, xnb);
    gemm_direct<<<dim3(4, 128), 256, 0, stream>>>(xnb, wob, bo, x, nullptr, x1, M, 512, 512, 2);
    ln_kernel<<<M / 4, 256, 0, stream>>>(x1, g2, bb2, qb);
    gemm_direct<<<dim3(16, 128), 256, 0, stream>>>(qb, w1b, b1, nullptr, hb, nullptr, M, 512, 2048, 1);
    gemm_direct<<<dim3(4, 128), 256, 0, stream>>>(hb, w2b, b2, x1, nullptr, out, M, 2048, 512, 2);
}

// Round 7
// 423.842 us; speedup vs baseline: 1.4823x; 1.4823x over previous
//
#include <hip/hip_runtime.h>

typedef __bf16 bf16x8 __attribute__((ext_vector_type(8)));
typedef unsigned short u16x8 __attribute__((ext_vector_type(8)));
typedef float f32x4 __attribute__((ext_vector_type(4)));
typedef unsigned short u16;

__device__ __forceinline__ float bf2f(u16 u) {
    union { unsigned int i; float f; } x; x.i = ((unsigned int)u) << 16; return x.f;
}
__device__ __forceinline__ u16 f2bf(float f) {
    union { float f; unsigned int i; } x; x.f = f;
    unsigned int u = x.i;
    unsigned int r = (u + 0x7FFFu + ((u >> 16) & 1u)) >> 16;
    return (u16)r;
}

#define GL16(g, l) __builtin_amdgcn_global_load_lds( \
    (__attribute__((address_space(1))) void*)(void*)(g), \
    (__attribute__((address_space(3))) void*)(void*)(l), 16, 0, 0)

// ---------------------------------------------------------------------------
// weights fp32 -> bf16
// ---------------------------------------------------------------------------
__global__ __launch_bounds__(256)
void cvt6_kernel(const float* __restrict__ s0, const float* __restrict__ s1,
                 const float* __restrict__ s2, const float* __restrict__ s3,
                 const float* __restrict__ s4, const float* __restrict__ s5,
                 u16* __restrict__ d0, u16* __restrict__ d1, u16* __restrict__ d2,
                 u16* __restrict__ d3, u16* __restrict__ d4, u16* __restrict__ d5)
{
    int b = blockIdx.x;
    const float* s; u16* d; int base;
    if (b < 512) {
        int t = b >> 7, lb = b & 127;
        s = (t == 0) ? s0 : (t == 1) ? s1 : (t == 2) ? s2 : s3;
        d = (t == 0) ? d0 : (t == 1) ? d1 : (t == 2) ? d2 : d3;
        base = lb * 2048;
    } else if (b < 1024) { s = s4; d = d4; base = (b - 512) * 2048; }
    else                 { s = s5; d = d5; base = (b - 1024) * 2048; }
    int i = base + threadIdx.x * 8;
    float4 a = *(const float4*)&s[i];
    float4 c = *(const float4*)&s[i + 4];
    u16x8 o;
    o[0] = f2bf(a.x); o[1] = f2bf(a.y); o[2] = f2bf(a.z); o[3] = f2bf(a.w);
    o[4] = f2bf(c.x); o[5] = f2bf(c.y); o[6] = f2bf(c.z); o[7] = f2bf(c.w);
    *(u16x8*)&d[i] = o;
}

// ---------------------------------------------------------------------------
// bias[i][j] = alpha*softmax_j(relu(E E^T)) + beta*lap + (lap!=0?0:-1e9)
// ---------------------------------------------------------------------------
__global__ __launch_bounds__(256)
void bias_kernel(const float* __restrict__ E, const float* __restrict__ lap,
                 const float* __restrict__ alpha_p, const float* __restrict__ beta_p,
                 float* __restrict__ biasout)
{
    __shared__ float wred[8];
    int tid = threadIdx.x;
    int i = blockIdx.x;
    int lane = tid & 63, wave = tid >> 6;
    int j0 = tid, j1 = tid + 256;
    float s0 = 0.f, s1 = 0.f;
#pragma unroll
    for (int t4 = 0; t4 < 16; ++t4) {
        float4 a  = *(const float4*)&E[i * 64 + t4 * 4];
        float4 e0 = *(const float4*)&E[j0 * 64 + t4 * 4];
        float4 e1 = *(const float4*)&E[j1 * 64 + t4 * 4];
        s0 += a.x * e0.x + a.y * e0.y + a.z * e0.z + a.w * e0.w;
        s1 += a.x * e1.x + a.y * e1.y + a.z * e1.z + a.w * e1.w;
    }
    s0 = fmaxf(s0, 0.f); s1 = fmaxf(s1, 0.f);
    float m = fmaxf(s0, s1);
#pragma unroll
    for (int o = 32; o > 0; o >>= 1) m = fmaxf(m, __shfl_xor(m, o));
    if (lane == 0) wred[wave] = m;
    __syncthreads();
    m = fmaxf(fmaxf(wred[0], wred[1]), fmaxf(wred[2], wred[3]));
    float e0v = __expf(s0 - m), e1v = __expf(s1 - m);
    float sum = e0v + e1v;
#pragma unroll
    for (int o = 32; o > 0; o >>= 1) sum += __shfl_xor(sum, o);
    if (lane == 0) wred[4 + wave] = sum;
    __syncthreads();
    float inv = 1.f / (wred[4] + wred[5] + wred[6] + wred[7]);
    float alpha = alpha_p[0], beta = beta_p[0];
    float lv0 = lap[i * 512 + j0];
    float lv1 = lap[i * 512 + j1];
    biasout[i * 512 + j0] = alpha * (e0v * inv) + beta * lv0 + (lv0 != 0.f ? 0.f : -1e9f);
    biasout[i * 512 + j1] = alpha * (e1v * inv) + beta * lv1 + (lv1 != 0.f ? 0.f : -1e9f);
}

// ---------------------------------------------------------------------------
// LayerNorm D=512, fp32 in, bf16 out
// ---------------------------------------------------------------------------
__global__ __launch_bounds__(256)
void ln_kernel(const float* __restrict__ X, const float* __restrict__ G,
               const float* __restrict__ Bb, u16* __restrict__ Y)
{
    int row = blockIdx.x * 4 + (threadIdx.x >> 6);
    int lane = threadIdx.x & 63;
    const float* xr = X + (size_t)row * 512 + lane * 8;
    float4 a = *(const float4*)xr;
    float4 b = *(const float4*)(xr + 4);
    float v[8] = {a.x, a.y, a.z, a.w, b.x, b.y, b.z, b.w};
    float s = 0.f, ss = 0.f;
#pragma unroll
    for (int i = 0; i < 8; i++) { s += v[i]; ss += v[i] * v[i]; }
#pragma unroll
    for (int o = 32; o > 0; o >>= 1) { s += __shfl_xor(s, o); ss += __shfl_xor(ss, o); }
    float mu = s * (1.f / 512.f);
    float var = ss * (1.f / 512.f) - mu * mu;
    float rstd = rsqrtf(var + 1e-5f);
    float4 g0 = *(const float4*)&G[lane * 8];
    float4 g1 = *(const float4*)&G[lane * 8 + 4];
    float4 b0 = *(const float4*)&Bb[lane * 8];
    float4 b1 = *(const float4*)&Bb[lane * 8 + 4];
    float gv[8] = {g0.x, g0.y, g0.z, g0.w, g1.x, g1.y, g1.z, g1.w};
    float bv[8] = {b0.x, b0.y, b0.z, b0.w, b1.x, b1.y, b1.z, b1.w};
    u16x8 out;
#pragma unroll
    for (int i = 0; i < 8; i++) out[i] = f2bf((v[i] - mu) * rstd * gv[i] + bv[i]);
    *(u16x8*)&Y[(size_t)row * 512 + lane * 8] = out;
}

// ---------------------------------------------------------------------------
// LDS GEMM (m97 pattern), 128x128 tile, XCD-swizzled.
// mode 0 plain->bf16, 1 relu->bf16, 2 +resid(fp32)->fp32
// ---------------------------------------------------------------------------
__global__ __launch_bounds__(256)
void gemm_bt(const u16* __restrict__ A, const u16* __restrict__ W,
             const float* __restrict__ bias, const float* __restrict__ resid,
             u16* __restrict__ Cb, float* __restrict__ Cf,
             int M, int Kd, int Nout, int mode)
{
    __shared__ __align__(16) u16 lA[128 * 32];
    __shared__ __align__(16) u16 lB[128 * 32];
    int tid = threadIdx.x;
    int lane = tid & 63, wave = tid >> 6;
    int wm = wave >> 1, wn = wave & 1;
    int bid = blockIdx.y * gridDim.x + blockIdx.x;
    int per = (gridDim.x * gridDim.y) >> 3;
    int lb  = (bid & 7) * per + (bid >> 3);
    int bx = lb % gridDim.x, by = lb / gridDim.x;
    int row0 = by * 128, col0 = bx * 128;
    int rl = lane & 15, kq = lane >> 4;
    f32x4 acc[4][4];
#pragma unroll
    for (int i = 0; i < 4; i++)
#pragma unroll
        for (int j = 0; j < 4; j++) acc[i][j] = (f32x4){0.f, 0.f, 0.f, 0.f};

    int c0 = tid,       sr0 = c0 >> 2, sc0 = (c0 & 3) * 8;
    int c1 = 256 + tid, sr1 = c1 >> 2, sc1 = (c1 & 3) * 8;
    const u16* Abase = A + (size_t)row0 * Kd;
    const u16* Wbase = W + (size_t)col0 * Kd;

    for (int k0 = 0; k0 < Kd; k0 += 32) {
        GL16(Abase + (size_t)sr0 * Kd + k0 + sc0, &lA[c0 * 8]);
        GL16(Abase + (size_t)sr1 * Kd + k0 + sc1, &lA[c1 * 8]);
        GL16(Wbase + (size_t)sr0 * Kd + k0 + sc0, &lB[c0 * 8]);
        GL16(Wbase + (size_t)sr1 * Kd + k0 + sc1, &lB[c1 * 8]);
        __syncthreads();
        bf16x8 af[4], bf[4];
#pragma unroll
        for (int i = 0; i < 4; i++) af[i] = *(const bf16x8*)&lA[(wm * 64 + i * 16 + rl) * 32 + kq * 8];
#pragma unroll
        for (int j = 0; j < 4; j++) bf[j] = *(const bf16x8*)&lB[(wn * 64 + j * 16 + rl) * 32 + kq * 8];
#pragma unroll
        for (int i = 0; i < 4; i++)
#pragma unroll
            for (int j = 0; j < 4; j++)
                acc[i][j] = __builtin_amdgcn_mfma_f32_16x16x32_bf16(af[i], bf[j], acc[i][j], 0, 0, 0);
        __syncthreads();
    }
#pragma unroll
    for (int j = 0; j < 4; j++) {
        int col = col0 + wn * 64 + j * 16 + rl;
        float bsv = bias[col];
#pragma unroll
        for (int i = 0; i < 4; i++) {
            int rbase = row0 + wm * 64 + i * 16 + kq * 4;
#pragma unroll
            for (int r = 0; r < 4; r++) {
                float vo = acc[i][j][r] + bsv;
                size_t idx = (size_t)(rbase + r) * Nout + col;
                if (mode == 2)      Cf[idx] = vo + resid[idx];
                else if (mode == 1) Cb[idx] = f2bf(fmaxf(vo, 0.f));
                else                Cb[idx] = f2bf(vo);
            }
        }
    }
}

// ---------------------------------------------------------------------------
// 64x128-tile LDS GEMM for grid-starved N=512 GEMMs (Wo, W2): 1024 blocks
// instead of 512 -> 4 blocks/CU for latency hiding. Waves 2x2, each 2x4 frags.
// ---------------------------------------------------------------------------
__global__ __launch_bounds__(256)
void gemm_bt64(const u16* __restrict__ A, const u16* __restrict__ W,
               const float* __restrict__ bias, const float* __restrict__ resid,
               u16* __restrict__ Cb, float* __restrict__ Cf,
               int M, int Kd, int Nout, int mode)
{
    __shared__ __align__(16) u16 lA[64 * 32];
    __shared__ __align__(16) u16 lB[128 * 32];
    int tid = threadIdx.x;
    int lane = tid & 63, wave = tid >> 6;
    int wm = wave >> 1, wn = wave & 1;
    int bid = blockIdx.y * gridDim.x + blockIdx.x;
    int per = (gridDim.x * gridDim.y) >> 3;
    int lb  = (bid & 7) * per + (bid >> 3);
    int bx = lb % gridDim.x, by = lb / gridDim.x;
    int row0 = by * 64, col0 = bx * 128;
    int rl = lane & 15, kq = lane >> 4;
    f32x4 acc[2][4];
#pragma unroll
    for (int i = 0; i < 2; i++)
#pragma unroll
        for (int j = 0; j < 4; j++) acc[i][j] = (f32x4){0.f, 0.f, 0.f, 0.f};

    // A: 64x32 = 256 chunks (1/thread); B: 128x32 = 512 chunks (2/thread)
    int cA = tid,       arow = cA >> 2, acol = (cA & 3) * 8;
    int c0 = tid,       sr0 = c0 >> 2, sc0 = (c0 & 3) * 8;
    int c1 = 256 + tid, sr1 = c1 >> 2, sc1 = (c1 & 3) * 8;
    const u16* Abase = A + (size_t)row0 * Kd;
    const u16* Wbase = W + (size_t)col0 * Kd;

    for (int k0 = 0; k0 < Kd; k0 += 32) {
        GL16(Abase + (size_t)arow * Kd + k0 + acol, &lA[cA * 8]);
        GL16(Wbase + (size_t)sr0 * Kd + k0 + sc0, &lB[c0 * 8]);
        GL16(Wbase + (size_t)sr1 * Kd + k0 + sc1, &lB[c1 * 8]);
        __syncthreads();
        bf16x8 af[2], bf[4];
#pragma unroll
        for (int i = 0; i < 2; i++) af[i] = *(const bf16x8*)&lA[(wm * 32 + i * 16 + rl) * 32 + kq * 8];
#pragma unroll
        for (int j = 0; j < 4; j++) bf[j] = *(const bf16x8*)&lB[(wn * 64 + j * 16 + rl) * 32 + kq * 8];
#pragma unroll
        for (int i = 0; i < 2; i++)
#pragma unroll
            for (int j = 0; j < 4; j++)
                acc[i][j] = __builtin_amdgcn_mfma_f32_16x16x32_bf16(af[i], bf[j], acc[i][j], 0, 0, 0);
        __syncthreads();
    }
#pragma unroll
    for (int j = 0; j < 4; j++) {
        int col = col0 + wn * 64 + j * 16 + rl;
        float bsv = bias[col];
#pragma unroll
        for (int i = 0; i < 2; i++) {
            int rbase = row0 + wm * 32 + i * 16 + kq * 4;
#pragma unroll
            for (int r = 0; r < 4; r++) {
                float vo = acc[i][j][r] + bsv;
                size_t idx = (size_t)(rbase + r) * Nout + col;
                if (mode == 2)      Cf[idx] = vo + resid[idx];
                else if (mode == 1) Cb[idx] = f2bf(fmaxf(vo, 0.f));
                else                Cb[idx] = f2bf(vo);
            }
        }
    }
}

// ---------------------------------------------------------------------------
// fused QKV, XCD-swizzled (round-5 version)
// ---------------------------------------------------------------------------
__global__ __launch_bounds__(256)
void gemm_qkv(const u16* __restrict__ A,
              const u16* __restrict__ W0, const u16* __restrict__ W1, const u16* __restrict__ W2,
              const float* __restrict__ b0, const float* __restrict__ b1, const float* __restrict__ b2,
              u16* __restrict__ C0, u16* __restrict__ C1, u16* __restrict__ C2)
{
    __shared__ __align__(16) u16 lA[128 * 32];
    __shared__ __align__(16) u16 lB[128 * 32];
    const int Kd = 512, Nout = 512;
    int bid = blockIdx.y * gridDim.x + blockIdx.x;
    int per = (gridDim.x * gridDim.y) >> 3;       // 192
    int lb  = (bid & 7) * per + (bid >> 3);
    int rest = lb % 12, by = lb / 12;
    int sel = rest >> 2;
    const u16* W = (sel == 0) ? W0 : (sel == 1) ? W1 : W2;
    const float* bias = (sel == 0) ? b0 : (sel == 1) ? b1 : b2;
    u16* Cb = (sel == 0) ? C0 : (sel == 1) ? C1 : C2;
    int tid = threadIdx.x;
    int lane = tid & 63, wave = tid >> 6;
    int wm = wave >> 1, wn = wave & 1;
    int row0 = by * 128, col0 = (rest & 3) * 128;
    int rl = lane & 15, kq = lane >> 4;
    f32x4 acc[4][4];
#pragma unroll
    for (int i = 0; i < 4; i++)
#pragma unroll
        for (int j = 0; j < 4; j++) acc[i][j] = (f32x4){0.f, 0.f, 0.f, 0.f};
    int c0 = tid,       sr0 = c0 >> 2, sc0 = (c0 & 3) * 8;
    int c1 = 256 + tid, sr1 = c1 >> 2, sc1 = (c1 & 3) * 8;
    const u16* Abase = A + (size_t)row0 * Kd;
    const u16* Wbase = W + (size_t)col0 * Kd;
    for (int k0 = 0; k0 < Kd; k0 += 32) {
        GL16(Abase + (size_t)sr0 * Kd + k0 + sc0, &lA[c0 * 8]);
        GL16(Abase + (size_t)sr1 * Kd + k0 + sc1, &lA[c1 * 8]);
        GL16(Wbase + (size_t)sr0 * Kd + k0 + sc0, &lB[c0 * 8]);
        GL16(Wbase + (size_t)sr1 * Kd + k0 + sc1, &lB[c1 * 8]);
        __syncthreads();
        bf16x8 af[4], bf[4];
#pragma unroll
        for (int i = 0; i < 4; i++) af[i] = *(const bf16x8*)&lA[(wm * 64 + i * 16 + rl) * 32 + kq * 8];
#pragma unroll
        for (int j = 0; j < 4; j++) bf[j] = *(const bf16x8*)&lB[(wn * 64 + j * 16 + rl) * 32 + kq * 8];
#pragma unroll
        for (int i = 0; i < 4; i++)
#pragma unroll
            for (int j = 0; j < 4; j++)
                acc[i][j] = __builtin_amdgcn_mfma_f32_16x16x32_bf16(af[i], bf[j], acc[i][j], 0, 0, 0);
        __syncthreads();
    }
#pragma unroll
    for (int j = 0; j < 4; j++) {
        int col = col0 + wn * 64 + j * 16 + rl;
        float bsv = bias[col];
#pragma unroll
        for (int i = 0; i < 4; i++) {
            int rbase = row0 + wm * 64 + i * 16 + kq * 4;
#pragma unroll
            for (int r = 0; r < 4; r++)
                Cb[(size_t)(rbase + r) * Nout + col] = f2bf(acc[i][j][r] + bsv);
        }
    }
}

// ---------------------------------------------------------------------------
// flash attention (round-5 version, verified)
// ---------------------------------------------------------------------------
__global__ __launch_bounds__(256, 2)
void flash_attn(const u16* __restrict__ Q, const u16* __restrict__ Km,
                const u16* __restrict__ V, const float* __restrict__ biasP,
                u16* __restrict__ O)
{
    __shared__ __align__(16) u16 lQ[128 * 64];
    __shared__ __align__(16) u16 lPK[128 * 136];
    __shared__ __align__(16) unsigned int lVt[64 * 68];
    __shared__ float red[2 * 128];
    __shared__ float m_s[128], l_s[128], alpha_s[128], mnew_s[128];

    int tid = threadIdx.x, lane = tid & 63, wave = tid >> 6;
    int wm = wave >> 1, wn = wave & 1;
    int rl = lane & 15, kq = lane >> 4;
    int qt = blockIdx.x, h = blockIdx.y, bt = blockIdx.z;
    int qg0 = qt * 128;
    size_t hb = (size_t)bt * (512 * 512) + h * 64;
    const u16* Qbase = Q + hb + (size_t)qg0 * 512;
    const u16* Kb0   = Km + hb;
    const u16* Vb0   = V + hb;

#pragma unroll
    for (int rep = 0; rep < 4; ++rep) {
        int c = rep * 256 + tid;
        int qr = c >> 3, d0 = (c & 7) * 8;
        GL16(Qbase + (size_t)qr * 512 + d0, &lQ[c * 8]);
    }
    if (tid < 128) { m_s[tid] = -3.0e38f; l_s[tid] = 0.f; }
    __syncthreads();

    bf16x8 af[4][2];
#pragma unroll
    for (int i = 0; i < 4; i++)
#pragma unroll
        for (int s = 0; s < 2; s++)
            af[i][s] = *(const bf16x8*)&lQ[(wm * 64 + i * 16 + rl) * 64 + s * 32 + kq * 8];

    f32x4 o[4][2];
#pragma unroll
    for (int i = 0; i < 4; i++)
#pragma unroll
        for (int jj = 0; jj < 2; jj++) o[i][jj] = (f32x4){0.f, 0.f, 0.f, 0.f};

    for (int t = 0; t < 4; ++t) {
        int kv0 = t * 128;
        __syncthreads();
        const u16* Kbase = Kb0 + (size_t)kv0 * 512;
#pragma unroll
        for (int rep = 0; rep < 4; ++rep) {
            int c = rep * 256 + tid;
            int kv = c >> 3, d0 = (c & 7) * 8;
            GL16(Kbase + (size_t)kv * 512 + d0, &lPK[c * 8]);
        }
        const u16* Vbase = Vb0 + (size_t)kv0 * 512;
#pragma unroll
        for (int rep = 0; rep < 2; ++rep) {
            int idx = rep * 256 + tid;
            int p = idx & 63, e0 = (idx >> 6) * 8;
            const u16* vp0 = Vbase + (size_t)(2 * p) * 512 + e0;
            u16x8 v0 = *(const u16x8*)vp0;
            u16x8 v1 = *(const u16x8*)(vp0 + 512);
#pragma unroll
            for (int u = 0; u < 8; ++u)
                lVt[(e0 + u) * 68 + p] = (unsigned)v0[u] | ((unsigned)v1[u] << 16);
        }
        __syncthreads();

        f32x4 acc[4][4];
#pragma unroll
        for (int j = 0; j < 4; ++j) {
            bf16x8 bk0 = *(const bf16x8*)&lPK[(wn * 64 + j * 16 + rl) * 64 + kq * 8];
            bf16x8 bk1 = *(const bf16x8*)&lPK[(wn * 64 + j * 16 + rl) * 64 + 32 + kq * 8];
#pragma unroll
            for (int i = 0; i < 4; ++i) {
                acc[i][j] = __builtin_amdgcn_mfma_f32_16x16x32_bf16(af[i][0], bk0,
                            (f32x4){0.f, 0.f, 0.f, 0.f}, 0, 0, 0);
                acc[i][j] = __builtin_amdgcn_mfma_f32_16x16x32_bf16(af[i][1], bk1, acc[i][j], 0, 0, 0);
            }
        }
#pragma unroll
        for (int i = 0; i < 4; ++i)
#pragma unroll
            for (int j = 0; j < 4; ++j) {
                int colg = kv0 + wn * 64 + j * 16 + rl;
                const float* bp = biasP + (size_t)(qg0 + wm * 64 + i * 16 + kq * 4) * 512 + colg;
#pragma unroll
                for (int r = 0; r < 4; ++r)
                    acc[i][j][r] = acc[i][j][r] * 0.125f + bp[(size_t)r * 512];
            }

#pragma unroll
        for (int i = 0; i < 4; ++i) {
            float mx[4];
#pragma unroll
            for (int r = 0; r < 4; ++r) {
                mx[r] = fmaxf(fmaxf(acc[i][0][r], acc[i][1][r]), fmaxf(acc[i][2][r], acc[i][3][r]));
#pragma unroll
                for (int off = 8; off > 0; off >>= 1) mx[r] = fmaxf(mx[r], __shfl_xor(mx[r], off));
            }
            if (rl == 0) {
#pragma unroll
                for (int r = 0; r < 4; ++r)
                    red[wn * 128 + wm * 64 + i * 16 + kq * 4 + r] = mx[r];
            }
        }
        __syncthreads();
        if (tid < 128) {
            float pm = fmaxf(red[tid], red[128 + tid]);
            float mo = m_s[tid];
            float mn = fmaxf(mo, pm);
            m_s[tid] = mn; mnew_s[tid] = mn;
            alpha_s[tid] = __expf(mo - mn);
        }
        __syncthreads();

#pragma unroll
        for (int i = 0; i < 4; ++i) {
            int rb = wm * 64 + i * 16 + kq * 4;
            float mn[4], al[4], sm[4];
#pragma unroll
            for (int r = 0; r < 4; ++r) { mn[r] = mnew_s[rb + r]; al[r] = alpha_s[rb + r]; sm[r] = 0.f; }
#pragma unroll
            for (int j = 0; j < 4; ++j) {
                int col = wn * 64 + j * 16 + rl;
#pragma unroll
                for (int r = 0; r < 4; ++r) {
                    float p = __expf(acc[i][j][r] - mn[r]);
                    sm[r] += p;
                    lPK[(rb + r) * 136 + col] = f2bf(p);
                }
            }
#pragma unroll
            for (int jj = 0; jj < 2; ++jj)
#pragma unroll
                for (int r = 0; r < 4; ++r) o[i][jj][r] *= al[r];
#pragma unroll
            for (int r = 0; r < 4; ++r) {
#pragma unroll
                for (int off = 8; off > 0; off >>= 1) sm[r] += __shfl_xor(sm[r], off);
            }
            if (rl == 0) {
#pragma unroll
                for (int r = 0; r < 4; ++r) red[wn * 128 + rb + r] = sm[r];
            }
        }
        __syncthreads();
        if (tid < 128) l_s[tid] = l_s[tid] * alpha_s[tid] + red[tid] + red[128 + tid];

#pragma unroll
        for (int ks = 0; ks < 4; ++ks) {
            bf16x8 aP[4], bV[2];
#pragma unroll
            for (int i = 0; i < 4; ++i)
                aP[i] = *(const bf16x8*)&lPK[(wm * 64 + i * 16 + rl) * 136 + ks * 32 + kq * 8];
#pragma unroll
            for (int jj = 0; jj < 2; ++jj)
                bV[jj] = *(const bf16x8*)&lVt[(wn * 32 + jj * 16 + rl) * 68 + ks * 16 + kq * 4];
#pragma unroll
            for (int i = 0; i < 4; ++i)
#pragma unroll
                for (int jj = 0; jj < 2; ++jj)
                    o[i][jj] = __builtin_amdgcn_mfma_f32_16x16x32_bf16(aP[i], bV[jj], o[i][jj], 0, 0, 0);
        }
    }
    __syncthreads();

    u16* Ob = O + hb + (size_t)qg0 * 512;
#pragma unroll
    for (int i = 0; i < 4; ++i) {
        int rb = wm * 64 + i * 16 + kq * 4;
        float il[4];
#pragma unroll
        for (int r = 0; r < 4; ++r) il[r] = 1.f / l_s[rb + r];
#pragma unroll
        for (int jj = 0; jj < 2; ++jj) {
            int e = wn * 32 + jj * 16 + rl;
#pragma unroll
            for (int r = 0; r < 4; ++r)
                Ob[(size_t)(rb + r) * 512 + e] = f2bf(o[i][jj][r] * il[r]);
        }
    }
}

// ---------------------------------------------------------------------------
extern "C" void kernel_launch(void* const* d_in, const int* in_sizes, int n_in,
                              void* d_out, int out_size, void* d_ws, size_t ws_size,
                              hipStream_t stream)
{
    const float* x     = (const float*)d_in[0];
    const float* lap   = (const float*)d_in[1];
    const float* emb   = (const float*)d_in[2];
    const float* Wq    = (const float*)d_in[3];
    const float* bq    = (const float*)d_in[4];
    const float* Wk    = (const float*)d_in[5];
    const float* bk    = (const float*)d_in[6];
    const float* Wv    = (const float*)d_in[7];
    const float* bvv   = (const float*)d_in[8];
    const float* g1    = (const float*)d_in[9];
    const float* bb1   = (const float*)d_in[10];
    const float* g2    = (const float*)d_in[11];
    const float* bb2   = (const float*)d_in[12];
    const float* alpha = (const float*)d_in[13];
    const float* beta  = (const float*)d_in[14];
    const float* Wo    = (const float*)d_in[15];
    const float* bo    = (const float*)d_in[16];
    const float* W1    = (const float*)d_in[17];
    const float* b1    = (const float*)d_in[18];
    const float* W2    = (const float*)d_in[19];
    const float* b2    = (const float*)d_in[20];
    float* out = (float*)d_out;

    const size_t SZ = (size_t)4 * 8 * 512 * 512;
    char* w = (char*)d_ws;
    float* bias = (float*)w;  w += (size_t)512 * 512 * 4;
    u16* wqb = (u16*)w; w += (size_t)512 * 512 * 2;
    u16* wkb = (u16*)w; w += (size_t)512 * 512 * 2;
    u16* wvb = (u16*)w; w += (size_t)512 * 512 * 2;
    u16* wob = (u16*)w; w += (size_t)512 * 512 * 2;
    u16* w1b = (u16*)w; w += (size_t)2048 * 512 * 2;
    u16* w2b = (u16*)w; w += (size_t)512 * 2048 * 2;
    u16* xnb = (u16*)w; w += SZ * 2;   // LN1 out; reused as attention output
    u16* qb  = (u16*)w; w += SZ * 2;   // Q; reused as LN2 out
    u16* kb  = (u16*)w; w += SZ * 2;
    u16* vb  = (u16*)w; w += SZ * 2;
    u16* hb  = (u16*)w; w += (size_t)16384 * 2048 * 2;
    float* x1 = out;

    const int M = 16384;
    cvt6_kernel<<<1536, 256, 0, stream>>>(Wq, Wk, Wv, Wo, W1, W2,
                                          wqb, wkb, wvb, wob, w1b, w2b);
    bias_kernel<<<512, 256, 0, stream>>>(emb, lap, alpha, beta, bias);
    ln_kernel<<<M / 4, 256, 0, stream>>>(x, g1, bb1, xnb);
    gemm_qkv<<<dim3(12, 128), 256, 0, stream>>>(xnb, wqb, wkb, wvb, bq, bk, bvv, qb, kb, vb);
    flash_attn<<<dim3(4, 8, 32), 256, 0, stream>>>(qb, kb, vb, bias, xnb);
    gemm_bt64<<<dim3(4, 256), 256, 0, stream>>>(xnb, wob, bo, x, nullptr, x1, M, 512, 512, 2);
    ln_kernel<<<M / 4, 256, 0, stream>>>(x1, g2, bb2, qb);
    gemm_bt<<<dim3(16, 128), 256, 0, stream>>>(qb, w1b, b1, nullptr, hb, nullptr, M, 512, 2048, 1);
    gemm_bt64<<<dim3(4, 256), 256, 0, stream>>>(hb, w2b, b2, x1, nullptr, out, M, 2048, 512, 2);
}

// Round 8
// 390.517 us; speedup vs baseline: 1.6088x; 1.0853x over previous
//
#include <hip/hip_runtime.h>

typedef __bf16 bf16x8 __attribute__((ext_vector_type(8)));
typedef unsigned short u16x8 __attribute__((ext_vector_type(8)));
typedef float f32x4 __attribute__((ext_vector_type(4)));
typedef unsigned short u16;

__device__ __forceinline__ float bf2f(u16 u) {
    union { unsigned int i; float f; } x; x.i = ((unsigned int)u) << 16; return x.f;
}
__device__ __forceinline__ u16 f2bf(float f) {
    union { float f; unsigned int i; } x; x.f = f;
    unsigned int u = x.i;
    unsigned int r = (u + 0x7FFFu + ((u >> 16) & 1u)) >> 16;
    return (u16)r;
}

#define GL16(g, l) __builtin_amdgcn_global_load_lds( \
    (__attribute__((address_space(1))) void*)(void*)(g), \
    (__attribute__((address_space(3))) void*)(void*)(l), 16, 0, 0)

// ---------------------------------------------------------------------------
// weights fp32 -> bf16
// ---------------------------------------------------------------------------
__global__ __launch_bounds__(256)
void cvt6_kernel(const float* __restrict__ s0, const float* __restrict__ s1,
                 const float* __restrict__ s2, const float* __restrict__ s3,
                 const float* __restrict__ s4, const float* __restrict__ s5,
                 u16* __restrict__ d0, u16* __restrict__ d1, u16* __restrict__ d2,
                 u16* __restrict__ d3, u16* __restrict__ d4, u16* __restrict__ d5)
{
    int b = blockIdx.x;
    const float* s; u16* d; int base;
    if (b < 512) {
        int t = b >> 7, lb = b & 127;
        s = (t == 0) ? s0 : (t == 1) ? s1 : (t == 2) ? s2 : s3;
        d = (t == 0) ? d0 : (t == 1) ? d1 : (t == 2) ? d2 : d3;
        base = lb * 2048;
    } else if (b < 1024) { s = s4; d = d4; base = (b - 512) * 2048; }
    else                 { s = s5; d = d5; base = (b - 1024) * 2048; }
    int i = base + threadIdx.x * 8;
    float4 a = *(const float4*)&s[i];
    float4 c = *(const float4*)&s[i + 4];
    u16x8 o;
    o[0] = f2bf(a.x); o[1] = f2bf(a.y); o[2] = f2bf(a.z); o[3] = f2bf(a.w);
    o[4] = f2bf(c.x); o[5] = f2bf(c.y); o[6] = f2bf(c.z); o[7] = f2bf(c.w);
    *(u16x8*)&d[i] = o;
}

// ---------------------------------------------------------------------------
// bias[i][j] = alpha*softmax_j(relu(E E^T)) + beta*lap + (lap!=0?0:-1e9)
// ---------------------------------------------------------------------------
__global__ __launch_bounds__(256)
void bias_kernel(const float* __restrict__ E, const float* __restrict__ lap,
                 const float* __restrict__ alpha_p, const float* __restrict__ beta_p,
                 float* __restrict__ biasout)
{
    __shared__ float wred[8];
    int tid = threadIdx.x;
    int i = blockIdx.x;
    int lane = tid & 63, wave = tid >> 6;
    int j0 = tid, j1 = tid + 256;
    float s0 = 0.f, s1 = 0.f;
#pragma unroll
    for (int t4 = 0; t4 < 16; ++t4) {
        float4 a  = *(const float4*)&E[i * 64 + t4 * 4];
        float4 e0 = *(const float4*)&E[j0 * 64 + t4 * 4];
        float4 e1 = *(const float4*)&E[j1 * 64 + t4 * 4];
        s0 += a.x * e0.x + a.y * e0.y + a.z * e0.z + a.w * e0.w;
        s1 += a.x * e1.x + a.y * e1.y + a.z * e1.z + a.w * e1.w;
    }
    s0 = fmaxf(s0, 0.f); s1 = fmaxf(s1, 0.f);
    float m = fmaxf(s0, s1);
#pragma unroll
    for (int o = 32; o > 0; o >>= 1) m = fmaxf(m, __shfl_xor(m, o));
    if (lane == 0) wred[wave] = m;
    __syncthreads();
    m = fmaxf(fmaxf(wred[0], wred[1]), fmaxf(wred[2], wred[3]));
    float e0v = __expf(s0 - m), e1v = __expf(s1 - m);
    float sum = e0v + e1v;
#pragma unroll
    for (int o = 32; o > 0; o >>= 1) sum += __shfl_xor(sum, o);
    if (lane == 0) wred[4 + wave] = sum;
    __syncthreads();
    float inv = 1.f / (wred[4] + wred[5] + wred[6] + wred[7]);
    float alpha = alpha_p[0], beta = beta_p[0];
    float lv0 = lap[i * 512 + j0];
    float lv1 = lap[i * 512 + j1];
    biasout[i * 512 + j0] = alpha * (e0v * inv) + beta * lv0 + (lv0 != 0.f ? 0.f : -1e9f);
    biasout[i * 512 + j1] = alpha * (e1v * inv) + beta * lv1 + (lv1 != 0.f ? 0.f : -1e9f);
}

// ---------------------------------------------------------------------------
// LayerNorm D=512, fp32 in, bf16 out
// ---------------------------------------------------------------------------
__global__ __launch_bounds__(256)
void ln_kernel(const float* __restrict__ X, const float* __restrict__ G,
               const float* __restrict__ Bb, u16* __restrict__ Y)
{
    int row = blockIdx.x * 4 + (threadIdx.x >> 6);
    int lane = threadIdx.x & 63;
    const float* xr = X + (size_t)row * 512 + lane * 8;
    float4 a = *(const float4*)xr;
    float4 b = *(const float4*)(xr + 4);
    float v[8] = {a.x, a.y, a.z, a.w, b.x, b.y, b.z, b.w};
    float s = 0.f, ss = 0.f;
#pragma unroll
    for (int i = 0; i < 8; i++) { s += v[i]; ss += v[i] * v[i]; }
#pragma unroll
    for (int o = 32; o > 0; o >>= 1) { s += __shfl_xor(s, o); ss += __shfl_xor(ss, o); }
    float mu = s * (1.f / 512.f);
    float var = ss * (1.f / 512.f) - mu * mu;
    float rstd = rsqrtf(var + 1e-5f);
    float4 g0 = *(const float4*)&G[lane * 8];
    float4 g1 = *(const float4*)&G[lane * 8 + 4];
    float4 b0 = *(const float4*)&Bb[lane * 8];
    float4 b1 = *(const float4*)&Bb[lane * 8 + 4];
    float gv[8] = {g0.x, g0.y, g0.z, g0.w, g1.x, g1.y, g1.z, g1.w};
    float bv[8] = {b0.x, b0.y, b0.z, b0.w, b1.x, b1.y, b1.z, b1.w};
    u16x8 out;
#pragma unroll
    for (int i = 0; i < 8; i++) out[i] = f2bf((v[i] - mu) * rstd * gv[i] + bv[i]);
    *(u16x8*)&Y[(size_t)row * 512 + lane * 8] = out;
}

// ---------------------------------------------------------------------------
// LDS GEMM (m97 pattern), 128x128 tile, XCD-swizzled, bf16 out (mode 0/1).
// Epilogue staged through LDS (stride 136) -> coalesced u16x8 global stores.
// ---------------------------------------------------------------------------
__global__ __launch_bounds__(256)
void gemm_bt(const u16* __restrict__ A, const u16* __restrict__ W,
             const float* __restrict__ bias,
             u16* __restrict__ Cb, int M, int Kd, int Nout, int mode)
{
    __shared__ __align__(16) char smem[128 * 136 * 2];   // 34 KB (>= lA+lB 16 KB)
    u16* lA = (u16*)smem;
    u16* lB = lA + 128 * 32;
    int tid = threadIdx.x;
    int lane = tid & 63, wave = tid >> 6;
    int wm = wave >> 1, wn = wave & 1;
    int bid = blockIdx.y * gridDim.x + blockIdx.x;
    int per = (gridDim.x * gridDim.y) >> 3;
    int lb  = (bid & 7) * per + (bid >> 3);
    int bx = lb % gridDim.x, by = lb / gridDim.x;
    int row0 = by * 128, col0 = bx * 128;
    int rl = lane & 15, kq = lane >> 4;
    f32x4 acc[4][4];
#pragma unroll
    for (int i = 0; i < 4; i++)
#pragma unroll
        for (int j = 0; j < 4; j++) acc[i][j] = (f32x4){0.f, 0.f, 0.f, 0.f};

    int c0 = tid,       sr0 = c0 >> 2, sc0 = (c0 & 3) * 8;
    int c1 = 256 + tid, sr1 = c1 >> 2, sc1 = (c1 & 3) * 8;
    const u16* Abase = A + (size_t)row0 * Kd;
    const u16* Wbase = W + (size_t)col0 * Kd;

    for (int k0 = 0; k0 < Kd; k0 += 32) {
        GL16(Abase + (size_t)sr0 * Kd + k0 + sc0, &lA[c0 * 8]);
        GL16(Abase + (size_t)sr1 * Kd + k0 + sc1, &lA[c1 * 8]);
        GL16(Wbase + (size_t)sr0 * Kd + k0 + sc0, &lB[c0 * 8]);
        GL16(Wbase + (size_t)sr1 * Kd + k0 + sc1, &lB[c1 * 8]);
        __syncthreads();
        bf16x8 af[4], bf[4];
#pragma unroll
        for (int i = 0; i < 4; i++) af[i] = *(const bf16x8*)&lA[(wm * 64 + i * 16 + rl) * 32 + kq * 8];
#pragma unroll
        for (int j = 0; j < 4; j++) bf[j] = *(const bf16x8*)&lB[(wn * 64 + j * 16 + rl) * 32 + kq * 8];
#pragma unroll
        for (int i = 0; i < 4; i++)
#pragma unroll
            for (int j = 0; j < 4; j++)
                acc[i][j] = __builtin_amdgcn_mfma_f32_16x16x32_bf16(af[i], bf[j], acc[i][j], 0, 0, 0);
        __syncthreads();
    }
    // epilogue: stage bf16 tile in LDS, then coalesced stores
    u16* lC = (u16*)smem;
#pragma unroll
    for (int j = 0; j < 4; j++) {
        int col = wn * 64 + j * 16 + rl;
        float bsv = bias[col0 + col];
#pragma unroll
        for (int i = 0; i < 4; i++) {
            int rb = wm * 64 + i * 16 + kq * 4;
#pragma unroll
            for (int r = 0; r < 4; r++) {
                float vo = acc[i][j][r] + bsv;
                if (mode == 1) vo = fmaxf(vo, 0.f);
                lC[(rb + r) * 136 + col] = f2bf(vo);
            }
        }
    }
    __syncthreads();
#pragma unroll
    for (int rep = 0; rep < 8; rep++) {
        int row = rep * 16 + (tid >> 4);
        int col8 = (tid & 15) * 8;
        *(u16x8*)&Cb[(size_t)(row0 + row) * Nout + col0 + col8] = *(const u16x8*)&lC[row * 136 + col8];
    }
}

// ---------------------------------------------------------------------------
// 64x128-tile LDS GEMM, fp32 out with residual (mode 2 semantics only).
// Epilogue staged through LDS (f32 stride 132) -> coalesced float4 rd/st.
// ---------------------------------------------------------------------------
__global__ __launch_bounds__(256)
void gemm_bt64(const u16* __restrict__ A, const u16* __restrict__ W,
               const float* __restrict__ bias, const float* __restrict__ resid,
               float* __restrict__ Cf, int M, int Kd, int Nout)
{
    __shared__ __align__(16) char smem[64 * 132 * 4];    // 33 KB (>= lA+lB 12 KB)
    u16* lA = (u16*)smem;
    u16* lB = lA + 64 * 32;
    int tid = threadIdx.x;
    int lane = tid & 63, wave = tid >> 6;
    int wm = wave >> 1, wn = wave & 1;
    int bid = blockIdx.y * gridDim.x + blockIdx.x;
    int per = (gridDim.x * gridDim.y) >> 3;
    int lb  = (bid & 7) * per + (bid >> 3);
    int bx = lb % gridDim.x, by = lb / gridDim.x;
    int row0 = by * 64, col0 = bx * 128;
    int rl = lane & 15, kq = lane >> 4;
    f32x4 acc[2][4];
#pragma unroll
    for (int i = 0; i < 2; i++)
#pragma unroll
        for (int j = 0; j < 4; j++) acc[i][j] = (f32x4){0.f, 0.f, 0.f, 0.f};

    int cA = tid,       arow = cA >> 2, acol = (cA & 3) * 8;
    int c0 = tid,       sr0 = c0 >> 2, sc0 = (c0 & 3) * 8;
    int c1 = 256 + tid, sr1 = c1 >> 2, sc1 = (c1 & 3) * 8;
    const u16* Abase = A + (size_t)row0 * Kd;
    const u16* Wbase = W + (size_t)col0 * Kd;

    for (int k0 = 0; k0 < Kd; k0 += 32) {
        GL16(Abase + (size_t)arow * Kd + k0 + acol, &lA[cA * 8]);
        GL16(Wbase + (size_t)sr0 * Kd + k0 + sc0, &lB[c0 * 8]);
        GL16(Wbase + (size_t)sr1 * Kd + k0 + sc1, &lB[c1 * 8]);
        __syncthreads();
        bf16x8 af[2], bf[4];
#pragma unroll
        for (int i = 0; i < 2; i++) af[i] = *(const bf16x8*)&lA[(wm * 32 + i * 16 + rl) * 32 + kq * 8];
#pragma unroll
        for (int j = 0; j < 4; j++) bf[j] = *(const bf16x8*)&lB[(wn * 64 + j * 16 + rl) * 32 + kq * 8];
#pragma unroll
        for (int i = 0; i < 2; i++)
#pragma unroll
            for (int j = 0; j < 4; j++)
                acc[i][j] = __builtin_amdgcn_mfma_f32_16x16x32_bf16(af[i], bf[j], acc[i][j], 0, 0, 0);
        __syncthreads();
    }
    float* lC = (float*)smem;
#pragma unroll
    for (int j = 0; j < 4; j++) {
        int col = wn * 64 + j * 16 + rl;
        float bsv = bias[col0 + col];
#pragma unroll
        for (int i = 0; i < 2; i++) {
            int rb = wm * 32 + i * 16 + kq * 4;
#pragma unroll
            for (int r = 0; r < 4; r++)
                lC[(rb + r) * 132 + col] = acc[i][j][r] + bsv;
        }
    }
    __syncthreads();
#pragma unroll
    for (int rep = 0; rep < 8; rep++) {
        int row = rep * 8 + (tid >> 5);
        int col4 = (tid & 31) * 4;
        size_t idx = (size_t)(row0 + row) * Nout + col0 + col4;
        float4 rv = *(const float4*)&resid[idx];
        float4 cv = *(const float4*)&lC[row * 132 + col4];
        cv.x += rv.x; cv.y += rv.y; cv.z += rv.z; cv.w += rv.w;
        *(float4*)&Cf[idx] = cv;
    }
}

// ---------------------------------------------------------------------------
// fused QKV, XCD-swizzled, LDS-staged epilogue
// ---------------------------------------------------------------------------
__global__ __launch_bounds__(256)
void gemm_qkv(const u16* __restrict__ A,
              const u16* __restrict__ W0, const u16* __restrict__ W1, const u16* __restrict__ W2,
              const float* __restrict__ b0, const float* __restrict__ b1, const float* __restrict__ b2,
              u16* __restrict__ C0, u16* __restrict__ C1, u16* __restrict__ C2)
{
    __shared__ __align__(16) char smem[128 * 136 * 2];   // 34 KB
    u16* lA = (u16*)smem;
    u16* lB = lA + 128 * 32;
    const int Kd = 512, Nout = 512;
    int bid = blockIdx.y * gridDim.x + blockIdx.x;
    int per = (gridDim.x * gridDim.y) >> 3;       // 192
    int lb  = (bid & 7) * per + (bid >> 3);
    int rest = lb % 12, by = lb / 12;
    int sel = rest >> 2;
    const u16* W = (sel == 0) ? W0 : (sel == 1) ? W1 : W2;
    const float* bias = (sel == 0) ? b0 : (sel == 1) ? b1 : b2;
    u16* Cb = (sel == 0) ? C0 : (sel == 1) ? C1 : C2;
    int tid = threadIdx.x;
    int lane = tid & 63, wave = tid >> 6;
    int wm = wave >> 1, wn = wave & 1;
    int row0 = by * 128, col0 = (rest & 3) * 128;
    int rl = lane & 15, kq = lane >> 4;
    f32x4 acc[4][4];
#pragma unroll
    for (int i = 0; i < 4; i++)
#pragma unroll
        for (int j = 0; j < 4; j++) acc[i][j] = (f32x4){0.f, 0.f, 0.f, 0.f};
    int c0 = tid,       sr0 = c0 >> 2, sc0 = (c0 & 3) * 8;
    int c1 = 256 + tid, sr1 = c1 >> 2, sc1 = (c1 & 3) * 8;
    const u16* Abase = A + (size_t)row0 * Kd;
    const u16* Wbase = W + (size_t)col0 * Kd;
    for (int k0 = 0; k0 < Kd; k0 += 32) {
        GL16(Abase + (size_t)sr0 * Kd + k0 + sc0, &lA[c0 * 8]);
        GL16(Abase + (size_t)sr1 * Kd + k0 + sc1, &lA[c1 * 8]);
        GL16(Wbase + (size_t)sr0 * Kd + k0 + sc0, &lB[c0 * 8]);
        GL16(Wbase + (size_t)sr1 * Kd + k0 + sc1, &lB[c1 * 8]);
        __syncthreads();
        bf16x8 af[4], bf[4];
#pragma unroll
        for (int i = 0; i < 4; i++) af[i] = *(const bf16x8*)&lA[(wm * 64 + i * 16 + rl) * 32 + kq * 8];
#pragma unroll
        for (int j = 0; j < 4; j++) bf[j] = *(const bf16x8*)&lB[(wn * 64 + j * 16 + rl) * 32 + kq * 8];
#pragma unroll
        for (int i = 0; i < 4; i++)
#pragma unroll
            for (int j = 0; j < 4; j++)
                acc[i][j] = __builtin_amdgcn_mfma_f32_16x16x32_bf16(af[i], bf[j], acc[i][j], 0, 0, 0);
        __syncthreads();
    }
    u16* lC = (u16*)smem;
#pragma unroll
    for (int j = 0; j < 4; j++) {
        int col = wn * 64 + j * 16 + rl;
        float bsv = bias[col0 + col];
#pragma unroll
        for (int i = 0; i < 4; i++) {
            int rb = wm * 64 + i * 16 + kq * 4;
#pragma unroll
            for (int r = 0; r < 4; r++)
                lC[(rb + r) * 136 + col] = f2bf(acc[i][j][r] + bsv);
        }
    }
    __syncthreads();
#pragma unroll
    for (int rep = 0; rep < 8; rep++) {
        int row = rep * 16 + (tid >> 4);
        int col8 = (tid & 15) * 8;
        *(u16x8*)&Cb[(size_t)(row0 + row) * Nout + col0 + col8] = *(const u16x8*)&lC[row * 136 + col8];
    }
}

// ---------------------------------------------------------------------------
// flash attention; O-write staged through lPK for coalesced stores
// ---------------------------------------------------------------------------
__global__ __launch_bounds__(256, 2)
void flash_attn(const u16* __restrict__ Q, const u16* __restrict__ Km,
                const u16* __restrict__ V, const float* __restrict__ biasP,
                u16* __restrict__ O)
{
    __shared__ __align__(16) u16 lQ[128 * 64];
    __shared__ __align__(16) u16 lPK[128 * 136];
    __shared__ __align__(16) unsigned int lVt[64 * 68];
    __shared__ float red[2 * 128];
    __shared__ float m_s[128], l_s[128], alpha_s[128], mnew_s[128];

    int tid = threadIdx.x, lane = tid & 63, wave = tid >> 6;
    int wm = wave >> 1, wn = wave & 1;
    int rl = lane & 15, kq = lane >> 4;
    int qt = blockIdx.x, h = blockIdx.y, bt = blockIdx.z;
    int qg0 = qt * 128;
    size_t hb = (size_t)bt * (512 * 512) + h * 64;
    const u16* Qbase = Q + hb + (size_t)qg0 * 512;
    const u16* Kb0   = Km + hb;
    const u16* Vb0   = V + hb;

#pragma unroll
    for (int rep = 0; rep < 4; ++rep) {
        int c = rep * 256 + tid;
        int qr = c >> 3, d0 = (c & 7) * 8;
        GL16(Qbase + (size_t)qr * 512 + d0, &lQ[c * 8]);
    }
    if (tid < 128) { m_s[tid] = -3.0e38f; l_s[tid] = 0.f; }
    __syncthreads();

    bf16x8 af[4][2];
#pragma unroll
    for (int i = 0; i < 4; i++)
#pragma unroll
        for (int s = 0; s < 2; s++)
            af[i][s] = *(const bf16x8*)&lQ[(wm * 64 + i * 16 + rl) * 64 + s * 32 + kq * 8];

    f32x4 o[4][2];
#pragma unroll
    for (int i = 0; i < 4; i++)
#pragma unroll
        for (int jj = 0; jj < 2; jj++) o[i][jj] = (f32x4){0.f, 0.f, 0.f, 0.f};

    for (int t = 0; t < 4; ++t) {
        int kv0 = t * 128;
        __syncthreads();
        const u16* Kbase = Kb0 + (size_t)kv0 * 512;
#pragma unroll
        for (int rep = 0; rep < 4; ++rep) {
            int c = rep * 256 + tid;
            int kv = c >> 3, d0 = (c & 7) * 8;
            GL16(Kbase + (size_t)kv * 512 + d0, &lPK[c * 8]);
        }
        const u16* Vbase = Vb0 + (size_t)kv0 * 512;
#pragma unroll
        for (int rep = 0; rep < 2; ++rep) {
            int idx = rep * 256 + tid;
            int p = idx & 63, e0 = (idx >> 6) * 8;
            const u16* vp0 = Vbase + (size_t)(2 * p) * 512 + e0;
            u16x8 v0 = *(const u16x8*)vp0;
            u16x8 v1 = *(const u16x8*)(vp0 + 512);
#pragma unroll
            for (int u = 0; u < 8; ++u)
                lVt[(e0 + u) * 68 + p] = (unsigned)v0[u] | ((unsigned)v1[u] << 16);
        }
        __syncthreads();

        f32x4 acc[4][4];
#pragma unroll
        for (int j = 0; j < 4; ++j) {
            bf16x8 bk0 = *(const bf16x8*)&lPK[(wn * 64 + j * 16 + rl) * 64 + kq * 8];
            bf16x8 bk1 = *(const bf16x8*)&lPK[(wn * 64 + j * 16 + rl) * 64 + 32 + kq * 8];
#pragma unroll
            for (int i = 0; i < 4; ++i) {
                acc[i][j] = __builtin_amdgcn_mfma_f32_16x16x32_bf16(af[i][0], bk0,
                            (f32x4){0.f, 0.f, 0.f, 0.f}, 0, 0, 0);
                acc[i][j] = __builtin_amdgcn_mfma_f32_16x16x32_bf16(af[i][1], bk1, acc[i][j], 0, 0, 0);
            }
        }
#pragma unroll
        for (int i = 0; i < 4; ++i)
#pragma unroll
            for (int j = 0; j < 4; ++j) {
                int colg = kv0 + wn * 64 + j * 16 + rl;
                const float* bp = biasP + (size_t)(qg0 + wm * 64 + i * 16 + kq * 4) * 512 + colg;
#pragma unroll
                for (int r = 0; r < 4; ++r)
                    acc[i][j][r] = acc[i][j][r] * 0.125f + bp[(size_t)r * 512];
            }

#pragma unroll
        for (int i = 0; i < 4; ++i) {
            float mx[4];
#pragma unroll
            for (int r = 0; r < 4; ++r) {
                mx[r] = fmaxf(fmaxf(acc[i][0][r], acc[i][1][r]), fmaxf(acc[i][2][r], acc[i][3][r]));
#pragma unroll
                for (int off = 8; off > 0; off >>= 1) mx[r] = fmaxf(mx[r], __shfl_xor(mx[r], off));
            }
            if (rl == 0) {
#pragma unroll
                for (int r = 0; r < 4; ++r)
                    red[wn * 128 + wm * 64 + i * 16 + kq * 4 + r] = mx[r];
            }
        }
        __syncthreads();
        if (tid < 128) {
            float pm = fmaxf(red[tid], red[128 + tid]);
            float mo = m_s[tid];
            float mn = fmaxf(mo, pm);
            m_s[tid] = mn; mnew_s[tid] = mn;
            alpha_s[tid] = __expf(mo - mn);
        }
        __syncthreads();

#pragma unroll
        for (int i = 0; i < 4; ++i) {
            int rb = wm * 64 + i * 16 + kq * 4;
            float mn[4], al[4], sm[4];
#pragma unroll
            for (int r = 0; r < 4; ++r) { mn[r] = mnew_s[rb + r]; al[r] = alpha_s[rb + r]; sm[r] = 0.f; }
#pragma unroll
            for (int j = 0; j < 4; ++j) {
                int col = wn * 64 + j * 16 + rl;
#pragma unroll
                for (int r = 0; r < 4; ++r) {
                    float p = __expf(acc[i][j][r] - mn[r]);
                    sm[r] += p;
                    lPK[(rb + r) * 136 + col] = f2bf(p);
                }
            }
#pragma unroll
            for (int jj = 0; jj < 2; ++jj)
#pragma unroll
                for (int r = 0; r < 4; ++r) o[i][jj][r] *= al[r];
#pragma unroll
            for (int r = 0; r < 4; ++r) {
#pragma unroll
                for (int off = 8; off > 0; off >>= 1) sm[r] += __shfl_xor(sm[r], off);
            }
            if (rl == 0) {
#pragma unroll
                for (int r = 0; r < 4; ++r) red[wn * 128 + rb + r] = sm[r];
            }
        }
        __syncthreads();
        if (tid < 128) l_s[tid] = l_s[tid] * alpha_s[tid] + red[tid] + red[128 + tid];

#pragma unroll
        for (int ks = 0; ks < 4; ++ks) {
            bf16x8 aP[4], bV[2];
#pragma unroll
            for (int i = 0; i < 4; ++i)
                aP[i] = *(const bf16x8*)&lPK[(wm * 64 + i * 16 + rl) * 136 + ks * 32 + kq * 8];
#pragma unroll
            for (int jj = 0; jj < 2; ++jj)
                bV[jj] = *(const bf16x8*)&lVt[(wn * 32 + jj * 16 + rl) * 68 + ks * 16 + kq * 4];
#pragma unroll
            for (int i = 0; i < 4; ++i)
#pragma unroll
                for (int jj = 0; jj < 2; ++jj)
                    o[i][jj] = __builtin_amdgcn_mfma_f32_16x16x32_bf16(aP[i], bV[jj], o[i][jj], 0, 0, 0);
        }
    }
    __syncthreads();

    // epilogue: stage O tile (128x64 bf16) in lPK, then coalesced stores
#pragma unroll
    for (int i = 0; i < 4; ++i) {
        int rb = wm * 64 + i * 16 + kq * 4;
        float il[4];
#pragma unroll
        for (int r = 0; r < 4; ++r) il[r] = 1.f / l_s[rb + r];
#pragma unroll
        for (int jj = 0; jj < 2; ++jj) {
            int e = wn * 32 + jj * 16 + rl;
#pragma unroll
            for (int r = 0; r < 4; ++r)
                lPK[(rb + r) * 136 + e] = f2bf(o[i][jj][r] * il[r]);
        }
    }
    __syncthreads();
    u16* Ob = O + hb + (size_t)qg0 * 512;
#pragma unroll
    for (int rep = 0; rep < 4; ++rep) {
        int row = rep * 32 + (tid >> 3);
        int col8 = (tid & 7) * 8;
        *(u16x8*)&Ob[(size_t)row * 512 + col8] = *(const u16x8*)&lPK[row * 136 + col8];
    }
}

// ---------------------------------------------------------------------------
extern "C" void kernel_launch(void* const* d_in, const int* in_sizes, int n_in,
                              void* d_out, int out_size, void* d_ws, size_t ws_size,
                              hipStream_t stream)
{
    const float* x     = (const float*)d_in[0];
    const float* lap   = (const float*)d_in[1];
    const float* emb   = (const float*)d_in[2];
    const float* Wq    = (const float*)d_in[3];
    const float* bq    = (const float*)d_in[4];
    const float* Wk    = (const float*)d_in[5];
    const float* bk    = (const float*)d_in[6];
    const float* Wv    = (const float*)d_in[7];
    const float* bvv   = (const float*)d_in[8];
    const float* g1    = (const float*)d_in[9];
    const float* bb1   = (const float*)d_in[10];
    const float* g2    = (const float*)d_in[11];
    const float* bb2   = (const float*)d_in[12];
    const float* alpha = (const float*)d_in[13];
    const float* beta  = (const float*)d_in[14];
    const float* Wo    = (const float*)d_in[15];
    const float* bo    = (const float*)d_in[16];
    const float* W1    = (const float*)d_in[17];
    const float* b1    = (const float*)d_in[18];
    const float* W2    = (const float*)d_in[19];
    const float* b2    = (const float*)d_in[20];
    float* out = (float*)d_out;

    const size_t SZ = (size_t)4 * 8 * 512 * 512;
    char* w = (char*)d_ws;
    float* bias = (float*)w;  w += (size_t)512 * 512 * 4;
    u16* wqb = (u16*)w; w += (size_t)512 * 512 * 2;
    u16* wkb = (u16*)w; w += (size_t)512 * 512 * 2;
    u16* wvb = (u16*)w; w += (size_t)512 * 512 * 2;
    u16* wob = (u16*)w; w += (size_t)512 * 512 * 2;
    u16* w1b = (u16*)w; w += (size_t)2048 * 512 * 2;
    u16* w2b = (u16*)w; w += (size_t)512 * 2048 * 2;
    u16* xnb = (u16*)w; w += SZ * 2;   // LN1 out; reused as attention output
    u16* qb  = (u16*)w; w += SZ * 2;   // Q; reused as LN2 out
    u16* kb  = (u16*)w; w += SZ * 2;
    u16* vb  = (u16*)w; w += SZ * 2;
    u16* hb  = (u16*)w; w += (size_t)16384 * 2048 * 2;
    float* x1 = out;

    const int M = 16384;
    cvt6_kernel<<<1536, 256, 0, stream>>>(Wq, Wk, Wv, Wo, W1, W2,
                                          wqb, wkb, wvb, wob, w1b, w2b);
    bias_kernel<<<512, 256, 0, stream>>>(emb, lap, alpha, beta, bias);
    ln_kernel<<<M / 4, 256, 0, stream>>>(x, g1, bb1, xnb);
    gemm_qkv<<<dim3(12, 128), 256, 0, stream>>>(xnb, wqb, wkb, wvb, bq, bk, bvv, qb, kb, vb);
    flash_attn<<<dim3(4, 8, 32), 256, 0, stream>>>(qb, kb, vb, bias, xnb);
    gemm_bt64<<<dim3(4, 256), 256, 0, stream>>>(xnb, wob, bo, x, x1, M, 512, 512);
    ln_kernel<<<M / 4, 256, 0, stream>>>(x1, g2, bb2, qb);
    gemm_bt<<<dim3(16, 128), 256, 0, stream>>>(qb, w1b, b1, hb, M, 512, 2048, 1);
    gemm_bt64<<<dim3(4, 256), 256, 0, stream>>>(hb, w2b, b2, x1, out, M, 2048, 512);
}